// Round 14
// baseline (569.224 us; speedup 1.0000x reference)
//
#include <hip/hip_runtime.h>
#include <hip/hip_bf16.h>
#include <hip/hip_fp8.h>

#define TT 200
#define UU 50
#define BB 8
#define DJ 1024   // D_JOINT
#define DE 512    // D_ENC / D_DEC
#define VV 1024
#define M_TOTAL (BB*TT*UU)   // 80000
#define MB 128               // M rows per block
#define NBLK 625             // 80000 / 128
#define WINV (1.0f/32.0f)    // undo W_fc fp8 pre-scale

typedef float f32x4 __attribute__((ext_vector_type(4)));

__device__ __forceinline__ float fast_tanh(float x) {
    float e = __expf(2.f * x);
    return 1.f - 2.f / (e + 1.f);
}

__device__ __forceinline__ unsigned char f2fp8(float x) {
    return __hip_fp8_e4m3(x).__x;   // OCP e4m3, satfinite
}

__device__ __forceinline__ unsigned long long tanh_pack_fp8(float4 e0, float4 e1, float4 d0, float4 d1) {
    unsigned long long r;
    r  = (unsigned long long)f2fp8(fast_tanh(e0.x + d0.x));
    r |= (unsigned long long)f2fp8(fast_tanh(e0.y + d0.y)) << 8;
    r |= (unsigned long long)f2fp8(fast_tanh(e0.z + d0.z)) << 16;
    r |= (unsigned long long)f2fp8(fast_tanh(e0.w + d0.w)) << 24;
    r |= (unsigned long long)f2fp8(fast_tanh(e1.x + d1.x)) << 32;
    r |= (unsigned long long)f2fp8(fast_tanh(e1.y + d1.y)) << 40;
    r |= (unsigned long long)f2fp8(fast_tanh(e1.z + d1.z)) << 48;
    r |= (unsigned long long)f2fp8(fast_tanh(e1.w + d1.w)) << 56;
    return r;
}

// ---------- kernel 1: fused prep (projections granule-major + W_fc fp8 granule-major) ----------
__global__ __launch_bounds__(256) void k_prep(const float* __restrict__ enc,
                                              const float* __restrict__ dec,
                                              const float* __restrict__ W_enc,
                                              const float* __restrict__ b_enc,
                                              const float* __restrict__ W_dec,
                                              const float* __restrict__ b_dec,
                                              const float* __restrict__ W_fc,
                                              float* __restrict__ encp,
                                              float* __restrict__ decp,
                                              unsigned char* __restrict__ wfc8) {
    const int bx = blockIdx.x, by = blockIdx.y;
    const int tid = threadIdx.x;
    if (bx >= 125) {
        const int wid = (bx - 125) * 4 + by;     // 0..255
        #pragma unroll
        for (int r = 0; r < 2; ++r) {
            const int G = wid * 512 + r * 256 + tid;   // 131072 granules
            const int gk = G >> 10, n = G & 1023;
            const float* src = W_fc + (size_t)n * DJ + gk * 8;
            float4 a = *(const float4*)(src);
            float4 b = *(const float4*)(src + 4);
            unsigned long long rr;
            rr  = (unsigned long long)f2fp8(a.x * 32.f);
            rr |= (unsigned long long)f2fp8(a.y * 32.f) << 8;
            rr |= (unsigned long long)f2fp8(a.z * 32.f) << 16;
            rr |= (unsigned long long)f2fp8(a.w * 32.f) << 24;
            rr |= (unsigned long long)f2fp8(b.x * 32.f) << 32;
            rr |= (unsigned long long)f2fp8(b.y * 32.f) << 40;
            rr |= (unsigned long long)f2fp8(b.z * 32.f) << 48;
            rr |= (unsigned long long)f2fp8(b.w * 32.f) << 56;
            *(unsigned long long*)(wfc8 + (size_t)G * 8) = rr;
        }
        return;
    }
    __shared__ float in_s[16][DE];
    const bool isDec = bx >= 100;
    const float* in  = isDec ? dec   : enc;
    const float* W   = isDec ? W_dec : W_enc;
    const float* bia = isDec ? b_dec : b_enc;
    float* out       = isDec ? decp  : encp;
    const int NR     = isDec ? (BB*UU) : (BB*TT);
    const int m0 = (isDec ? (bx - 100) : bx) * 16;
    #pragma unroll
    for (int it = 0; it < 8; ++it) {
        int idx = tid + it * 256;
        int r = idx >> 7, c = (idx & 127) << 2;
        *(float4*)&in_s[r][c] = *(const float4*)(in + (size_t)(m0 + r) * DE + c);
    }
    __syncthreads();
    const int j = by * 256 + tid;
    const float4* wr = (const float4*)(W + (size_t)j * DE);
    float acc[16];
    #pragma unroll
    for (int r = 0; r < 16; ++r) acc[r] = 0.f;
    for (int d4 = 0; d4 < DE / 4; ++d4) {
        float4 w = wr[d4];
        #pragma unroll
        for (int r = 0; r < 16; ++r) {
            float4 x = *(const float4*)&in_s[r][d4 << 2];
            acc[r] += x.x * w.x + x.y * w.y + x.z * w.z + x.w * w.w;
        }
    }
    float bv = bia[j];
    const int gk = j >> 3, kl = j & 7;
    #pragma unroll
    for (int r = 0; r < 16; ++r)
        out[((size_t)gk * NR + (m0 + r)) * 8 + kl] = acc[r] + bv;
}

// ---------- kernel 2: fused tanh(enc+dec) @ W_fc^T + b_fc -> log_softmax ----------
// 512 threads (8 waves). Block: 128 M x 1024 N, processed as TWO N-halves of 512
// (acc = 8x4 frags = 128 f32 per half) -> MB doubles to 128 -> shared-W_fc L2
// traffic drops 1 GB -> 625 MB (the measured ~5.6 TB/s wall is the binding limit).
// A-stripe (128 KB fp8, tanh'd once) serves both halves. Softmax across halves:
// half-0 raw logits staged in d_out, fixed up (same-thread same-address) after lse.
__global__ __launch_bounds__(512, 2) void k_joint(const float* __restrict__ encp,
                                                  const float* __restrict__ decp,
                                                  const unsigned char* __restrict__ wfc8,
                                                  const float* __restrict__ bfc,
                                                  float* __restrict__ out) {
    __shared__ unsigned char As[131072];     // 128 KB: granule (gkf 0..127, m 0..127)
    __shared__ float red[8][MB];             // 4 KB
    __shared__ float m0s[MB], s0s[MB], lsem[MB], lsef[MB];   // 2 KB

    const int tid = threadIdx.x;
    const int wave = tid >> 6, lane = tid & 63;
    const int g = lane >> 4, ln = lane & 15;
    const int bid = blockIdx.x;
    const int m0 = bid * MB;

    // ---- prologue: compute A-stripe (tanh -> fp8) into LDS ----
    for (int r = 0; r < 32; ++r) {
        const int gidx = r * 512 + tid;          // 16384 granules: gkf*128 + m
        const int gkf = gidx >> 7;
        const int m = gidx & 127;
        const int mrow = m0 + m;
        const int b = mrow / (TT * UU);
        const int rem = mrow - b * (TT * UU);
        const int t = rem / UU;
        const int u = rem - t * UU;
        const float* ep = encp + ((size_t)gkf * (BB * TT) + b * TT + t) * 8;
        const float* dp = decp + ((size_t)gkf * (BB * UU) + b * UU + u) * 8;
        float4 e0 = *(const float4*)(ep);
        float4 e1 = *(const float4*)(ep + 4);
        float4 d0 = *(const float4*)(dp);
        float4 d1 = *(const float4*)(dp + 4);
        *(unsigned long long*)&As[(size_t)gidx * 8] = tanh_pack_fp8(e0, e1, d0, d1);
    }
    __syncthreads();

    // static per-lane bases
    const unsigned char* ap = As + g * 1024 + ln * 8;                  // + kb*4096 + mf*128
    const unsigned char* bp = wfc8 + g * 8192 + wave * 512 + ln * 8;   // + h*4096 + kb*32768 + nf*128

    f32x4 acc[8][4];

#define KLOOP(H)                                                                          \
    do {                                                                                  \
        _Pragma("unroll")                                                                 \
        for (int kb = 0; kb < 32; ++kb) {                                                 \
            long afr[8];                                                                  \
            _Pragma("unroll")                                                             \
            for (int mf = 0; mf < 8; ++mf)                                                \
                afr[mf] = *(const long*)(ap + kb * 4096 + mf * 128);                      \
            _Pragma("unroll")                                                             \
            for (int nf = 0; nf < 4; ++nf) {                                              \
                long bfr = *(const long*)(bp + (H) * 4096 + (size_t)kb * 32768 + nf * 128); \
                _Pragma("unroll")                                                         \
                for (int mf = 0; mf < 8; ++mf)                                            \
                    acc[mf][nf] = __builtin_amdgcn_mfma_f32_16x16x32_fp8_fp8(             \
                        afr[mf], bfr, acc[mf][nf], 0, 0, 0);                              \
            }                                                                             \
        }                                                                                 \
    } while (0)

    // ================= half 0 (cols 0..511) =================
    #pragma unroll
    for (int mf = 0; mf < 8; ++mf)
        #pragma unroll
        for (int nf = 0; nf < 4; ++nf)
            acc[mf][nf] = (f32x4){0.f, 0.f, 0.f, 0.f};
    KLOOP(0);

    {
        float bv[4];
        #pragma unroll
        for (int nf = 0; nf < 4; ++nf) bv[nf] = bfc[wave * 64 + nf * 16 + ln];
        #pragma unroll
        for (int mf = 0; mf < 8; ++mf)
            #pragma unroll
            for (int nf = 0; nf < 4; ++nf)
                #pragma unroll
                for (int j = 0; j < 4; ++j)
                    acc[mf][nf][j] = acc[mf][nf][j] * WINV + bv[nf];
    }
    // partial row max
    #pragma unroll
    for (int mf = 0; mf < 8; ++mf)
        #pragma unroll
        for (int j = 0; j < 4; ++j) {
            float mx = fmaxf(fmaxf(acc[mf][0][j], acc[mf][1][j]), fmaxf(acc[mf][2][j], acc[mf][3][j]));
            #pragma unroll
            for (int s = 1; s < 16; s <<= 1) mx = fmaxf(mx, __shfl_xor(mx, s));
            if (ln == 0) red[wave][mf * 16 + g * 4 + j] = mx;
        }
    __syncthreads();
    if (tid < MB) {
        float m = red[0][tid];
        #pragma unroll
        for (int w = 1; w < 8; ++w) m = fmaxf(m, red[w][tid]);
        m0s[tid] = m;
    }
    __syncthreads();
    // partial exp-sum (vs m0)
    #pragma unroll
    for (int mf = 0; mf < 8; ++mf)
        #pragma unroll
        for (int j = 0; j < 4; ++j) {
            const int r = mf * 16 + g * 4 + j;
            const float rm = m0s[r];
            float s = __expf(acc[mf][0][j] - rm) + __expf(acc[mf][1][j] - rm)
                    + __expf(acc[mf][2][j] - rm) + __expf(acc[mf][3][j] - rm);
            #pragma unroll
            for (int t2 = 1; t2 < 16; t2 <<= 1) s += __shfl_xor(s, t2);
            if (ln == 0) red[wave][r] = s;
        }
    __syncthreads();
    if (tid < MB) {
        float s = 0.f;
        #pragma unroll
        for (int w = 0; w < 8; ++w) s += red[w][tid];
        s0s[tid] = s;
    }
    // store half-0 RAW logits (fixed up after lse is known)
    #pragma unroll
    for (int mf = 0; mf < 8; ++mf)
        #pragma unroll
        for (int j = 0; j < 4; ++j) {
            const int r = mf * 16 + g * 4 + j;
            float* op = out + (size_t)(m0 + r) * VV + wave * 64 + ln;
            #pragma unroll
            for (int nf = 0; nf < 4; ++nf)
                op[nf * 16] = acc[mf][nf][j];
        }
    __syncthreads();   // red/m0s/s0s settled before half-1 reuses red

    // ================= half 1 (cols 512..1023) =================
    #pragma unroll
    for (int mf = 0; mf < 8; ++mf)
        #pragma unroll
        for (int nf = 0; nf < 4; ++nf)
            acc[mf][nf] = (f32x4){0.f, 0.f, 0.f, 0.f};
    KLOOP(1);
#undef KLOOP

    {
        float bv[4];
        #pragma unroll
        for (int nf = 0; nf < 4; ++nf) bv[nf] = bfc[512 + wave * 64 + nf * 16 + ln];
        #pragma unroll
        for (int mf = 0; mf < 8; ++mf)
            #pragma unroll
            for (int nf = 0; nf < 4; ++nf)
                #pragma unroll
                for (int j = 0; j < 4; ++j)
                    acc[mf][nf][j] = acc[mf][nf][j] * WINV + bv[nf];
    }
    #pragma unroll
    for (int mf = 0; mf < 8; ++mf)
        #pragma unroll
        for (int j = 0; j < 4; ++j) {
            float mx = fmaxf(fmaxf(acc[mf][0][j], acc[mf][1][j]), fmaxf(acc[mf][2][j], acc[mf][3][j]));
            #pragma unroll
            for (int s = 1; s < 16; s <<= 1) mx = fmaxf(mx, __shfl_xor(mx, s));
            if (ln == 0) red[wave][mf * 16 + g * 4 + j] = mx;
        }
    __syncthreads();
    if (tid < MB) {
        float m1 = red[0][tid];
        #pragma unroll
        for (int w = 1; w < 8; ++w) m1 = fmaxf(m1, red[w][tid]);
        lsem[tid] = fmaxf(m0s[tid], m1);
    }
    __syncthreads();
    #pragma unroll
    for (int mf = 0; mf < 8; ++mf)
        #pragma unroll
        for (int j = 0; j < 4; ++j) {
            const int r = mf * 16 + g * 4 + j;
            const float rm = lsem[r];
            float s = __expf(acc[mf][0][j] - rm) + __expf(acc[mf][1][j] - rm)
                    + __expf(acc[mf][2][j] - rm) + __expf(acc[mf][3][j] - rm);
            #pragma unroll
            for (int t2 = 1; t2 < 16; t2 <<= 1) s += __shfl_xor(s, t2);
            if (ln == 0) red[wave][r] = s;
        }
    __syncthreads();
    if (tid < MB) {
        float s = s0s[tid] * __expf(m0s[tid] - lsem[tid]);
        #pragma unroll
        for (int w = 0; w < 8; ++w) s += red[w][tid];
        lsef[tid] = lsem[tid] + __logf(s);
    }
    __syncthreads();

    // store half-1 final; fix up half-0 (same thread re-reads its own addresses)
    #pragma unroll
    for (int mf = 0; mf < 8; ++mf)
        #pragma unroll
        for (int j = 0; j < 4; ++j) {
            const int r = mf * 16 + g * 4 + j;
            const float L = lsef[r];
            float* op1 = out + (size_t)(m0 + r) * VV + 512 + wave * 64 + ln;
            #pragma unroll
            for (int nf = 0; nf < 4; ++nf)
                __builtin_nontemporal_store(acc[mf][nf][j] - L, op1 + nf * 16);
            float* op0 = out + (size_t)(m0 + r) * VV + wave * 64 + ln;
            #pragma unroll
            for (int nf = 0; nf < 4; ++nf) {
                float v = op0[nf * 16];
                __builtin_nontemporal_store(v - L, op0 + nf * 16);
            }
        }
}

extern "C" void kernel_launch(void* const* d_in, const int* in_sizes, int n_in,
                              void* d_out, int out_size, void* d_ws, size_t ws_size,
                              hipStream_t stream) {
    const float* enc   = (const float*)d_in[0];
    const float* dec   = (const float*)d_in[1];
    const float* W_enc = (const float*)d_in[2];
    const float* b_enc = (const float*)d_in[3];
    const float* W_dec = (const float*)d_in[4];
    const float* b_dec = (const float*)d_in[5];
    const float* W_fc  = (const float*)d_in[6];
    const float* b_fc  = (const float*)d_in[7];
    float* out = (float*)d_out;

    float* encp = (float*)d_ws;                               // 1600*1024 f32, granule-major
    float* decp = encp + (size_t)BB * TT * DJ;                //  400*1024 f32, granule-major
    unsigned char* wfc8 = (unsigned char*)(decp + (size_t)BB * UU * DJ);  // 1 MB fp8, granule-major
    // total ws: 9.2 MB (same footprint as passing rounds)

    k_prep<<<dim3(189, 4), 256, 0, stream>>>(enc, dec, W_enc, b_enc, W_dec, b_dec, W_fc,
                                             encp, decp, wfc8);
    k_joint<<<NBLK, 512, 0, stream>>>(encp, decp, wfc8, b_fc, out);
}

// Round 15
// 339.456 us; speedup vs baseline: 1.6769x; 1.6769x over previous
//
#include <hip/hip_runtime.h>
#include <hip/hip_bf16.h>
#include <hip/hip_fp8.h>

#define TT 200
#define UU 50
#define BB 8
#define DJ 1024   // D_JOINT
#define DE 512    // D_ENC / D_DEC
#define VV 1024
#define M_TOTAL (BB*TT*UU)   // 80000
#define MB 80                // M rows per block
#define NITER 32             // K / 32
#define WINV (1.0f/32.0f)    // undo W_fc fp8 pre-scale
// per-wave private B buffers in LDS
#define ROWPAD 1040          // 1 KB row + 16B pad (bank stagger across g)
#define BUFHALF (4*ROWPAD)   // 4160 B: one K-chunk slice for one wave
#define BUFW (2*BUFHALF)     // 8320 B per wave (double buffer)

typedef float f32x4 __attribute__((ext_vector_type(4)));

__device__ __forceinline__ float fast_tanh(float x) {
    float e = __expf(2.f * x);
    return 1.f - 2.f / (e + 1.f);
}

__device__ __forceinline__ unsigned char f2fp8(float x) {
    return __hip_fp8_e4m3(x).__x;   // OCP e4m3, satfinite
}

__device__ __forceinline__ unsigned long long tanh_pack_fp8(float4 e0, float4 e1, float4 d0, float4 d1) {
    unsigned long long r;
    r  = (unsigned long long)f2fp8(fast_tanh(e0.x + d0.x));
    r |= (unsigned long long)f2fp8(fast_tanh(e0.y + d0.y)) << 8;
    r |= (unsigned long long)f2fp8(fast_tanh(e0.z + d0.z)) << 16;
    r |= (unsigned long long)f2fp8(fast_tanh(e0.w + d0.w)) << 24;
    r |= (unsigned long long)f2fp8(fast_tanh(e1.x + d1.x)) << 32;
    r |= (unsigned long long)f2fp8(fast_tanh(e1.y + d1.y)) << 40;
    r |= (unsigned long long)f2fp8(fast_tanh(e1.z + d1.z)) << 48;
    r |= (unsigned long long)f2fp8(fast_tanh(e1.w + d1.w)) << 56;
    return r;
}

__device__ __forceinline__ void gload_lds16(const unsigned char* g, unsigned char* l) {
    __builtin_amdgcn_global_load_lds(
        (const __attribute__((address_space(1))) unsigned int*)(const void*)g,
        (__attribute__((address_space(3))) unsigned int*)(void*)l, 16, 0, 0);
}

// ---------- kernel 1: fused prep ----------
// bx<100: enc proj; 100..124: dec proj (both granule-major f32 [gk][rows][8]);
// bx>=125: W_fc fp32 [n][k] -> fp8 e4m3 (x32) granule-major [gk][n]
__global__ __launch_bounds__(256) void k_prep(const float* __restrict__ enc,
                                              const float* __restrict__ dec,
                                              const float* __restrict__ W_enc,
                                              const float* __restrict__ b_enc,
                                              const float* __restrict__ W_dec,
                                              const float* __restrict__ b_dec,
                                              const float* __restrict__ W_fc,
                                              float* __restrict__ encp,
                                              float* __restrict__ decp,
                                              unsigned char* __restrict__ wfc8) {
    const int bx = blockIdx.x, by = blockIdx.y;
    const int tid = threadIdx.x;
    if (bx >= 125) {
        const int wid = (bx - 125) * 4 + by;     // 0..255
        #pragma unroll
        for (int r = 0; r < 2; ++r) {
            const int G = wid * 512 + r * 256 + tid;   // 131072 granules
            const int gk = G >> 10, n = G & 1023;
            const float* src = W_fc + (size_t)n * DJ + gk * 8;
            float4 a = *(const float4*)(src);
            float4 b = *(const float4*)(src + 4);
            unsigned long long rr;
            rr  = (unsigned long long)f2fp8(a.x * 32.f);
            rr |= (unsigned long long)f2fp8(a.y * 32.f) << 8;
            rr |= (unsigned long long)f2fp8(a.z * 32.f) << 16;
            rr |= (unsigned long long)f2fp8(a.w * 32.f) << 24;
            rr |= (unsigned long long)f2fp8(b.x * 32.f) << 32;
            rr |= (unsigned long long)f2fp8(b.y * 32.f) << 40;
            rr |= (unsigned long long)f2fp8(b.z * 32.f) << 48;
            rr |= (unsigned long long)f2fp8(b.w * 32.f) << 56;
            *(unsigned long long*)(wfc8 + (size_t)G * 8) = rr;
        }
        return;
    }
    __shared__ float in_s[16][DE];
    const bool isDec = bx >= 100;
    const float* in  = isDec ? dec   : enc;
    const float* W   = isDec ? W_dec : W_enc;
    const float* bia = isDec ? b_dec : b_enc;
    float* out       = isDec ? decp  : encp;
    const int NR     = isDec ? (BB*UU) : (BB*TT);
    const int m0 = (isDec ? (bx - 100) : bx) * 16;
    #pragma unroll
    for (int it = 0; it < 8; ++it) {
        int idx = tid + it * 256;
        int r = idx >> 7, c = (idx & 127) << 2;
        *(float4*)&in_s[r][c] = *(const float4*)(in + (size_t)(m0 + r) * DE + c);
    }
    __syncthreads();
    const int j = by * 256 + tid;
    const float4* wr = (const float4*)(W + (size_t)j * DE);
    float acc[16];
    #pragma unroll
    for (int r = 0; r < 16; ++r) acc[r] = 0.f;
    for (int d4 = 0; d4 < DE / 4; ++d4) {
        float4 w = wr[d4];
        #pragma unroll
        for (int r = 0; r < 16; ++r) {
            float4 x = *(const float4*)&in_s[r][d4 << 2];
            acc[r] += x.x * w.x + x.y * w.y + x.z * w.z + x.w * w.w;
        }
    }
    float bv = bia[j];
    const int gk = j >> 3, kl = j & 7;
    #pragma unroll
    for (int r = 0; r < 16; ++r)
        out[((size_t)gk * NR + (m0 + r)) * 8 + kl] = acc[r] + bv;
}

// ---------- kernel 2: fused tanh(enc+dec) @ W_fc^T + b_fc -> log_softmax ----------
// 512 threads (8 waves), 80 M x 1024 N, fp8 GEMM. NO barriers in the main loop.
// B delivery via per-wave PRIVATE double-buffered LDS DMA (global_load_lds) with
// counted per-wave vmcnt(4): each wave issues 4 DMAs (4 KB, contiguous 1 KB rows)
// for iter t+1, waits only for iter t's 4, reads, MFMAs. No VGPR prefetch pressure,
// no cross-wave rendezvous; DMA latency hides under the ~1576-cyc MFMA phase.
__global__ __launch_bounds__(512, 2) void k_joint(const float* __restrict__ encp,
                                                  const float* __restrict__ decp,
                                                  const unsigned char* __restrict__ wfc8,
                                                  const float* __restrict__ bfc,
                                                  float* __restrict__ out) {
    __shared__ unsigned char As[81920];          // 80 KB: granule (gkf 0..127, m 0..79)
    __shared__ unsigned char Bw[8 * BUFW];       // 65 KB: per-wave private dbuf
    __shared__ float red[8][MB];                 // 2.5 KB   (total ~148 KB)

    const int tid = threadIdx.x;
    const int wave = tid >> 6, lane = tid & 63;
    const int g = lane >> 4, ln = lane & 15;
    const int bid = blockIdx.x;
    const int m0 = bid * MB;

    // ---- prologue: compute A-stripe (tanh -> fp8) into LDS ----
    for (int r = 0; r < 20; ++r) {
        const int gidx = r * 512 + tid;          // 10240 granules: gkf*80 + m
        const int gkf = gidx / MB;
        const int m = gidx - gkf * MB;
        const int mrow = m0 + m;
        const int b = mrow / (TT * UU);
        const int rem = mrow - b * (TT * UU);
        const int t = rem / UU;
        const int u = rem - t * UU;
        const float* ep = encp + ((size_t)gkf * (BB * TT) + b * TT + t) * 8;
        const float* dp = decp + ((size_t)gkf * (BB * UU) + b * UU + u) * 8;
        float4 e0 = *(const float4*)(ep);
        float4 e1 = *(const float4*)(ep + 4);
        float4 d0 = *(const float4*)(dp);
        float4 d1 = *(const float4*)(dp + 4);
        *(unsigned long long*)&As[(size_t)gidx * 8] = tanh_pack_fp8(e0, e1, d0, d1);
    }

    f32x4 acc[5][8];
    #pragma unroll
    for (int mf = 0; mf < 5; ++mf)
        #pragma unroll
        for (int nf = 0; nf < 8; ++nf)
            acc[mf][nf] = (f32x4){0.f, 0.f, 0.f, 0.f};

    __syncthreads();   // As ready; the ONLY block-wide barrier before epilogue

    // per-wave bases
    // global: granule row gk spans 8 KB; wave's slice = wfc8 + gk*8192 + wave*1024 (+lane*16)
    const unsigned char* gsrc = wfc8 + wave * 1024 + lane * 16;    // + (t*4+gg)*8192
    unsigned char* ldst = Bw + wave * BUFW + lane * 16;            // + half*BUFHALF + gg*ROWPAD
    // ds_read base for this thread's fragments
    const unsigned char* brd = Bw + wave * BUFW + g * ROWPAD + ln * 8;  // + half*BUFHALF + nf*128
    const unsigned char* ap = As + g * 640 + ln * 8;                    // + t*2560 + mf*128

    // DMA(0) into half 0
    #pragma unroll
    for (int gg = 0; gg < 4; ++gg)
        gload_lds16(gsrc + (size_t)gg * 8192, ldst + gg * ROWPAD);

    #pragma unroll
    for (int t = 0; t < NITER; ++t) {
        const int cur = t & 1, nxt = cur ^ 1;
        if (t < NITER - 1) {
            // issue DMA(t+1) into the other half (its iter t-1 reads are long complete)
            #pragma unroll
            for (int gg = 0; gg < 4; ++gg)
                gload_lds16(gsrc + (size_t)((t + 1) * 4 + gg) * 8192,
                            ldst + nxt * BUFHALF + gg * ROWPAD);
            asm volatile("s_waitcnt vmcnt(4)" ::: "memory");   // DMA(t) landed
        } else {
            asm volatile("s_waitcnt vmcnt(0)" ::: "memory");
        }
        long afr[5];
        #pragma unroll
        for (int mf = 0; mf < 5; ++mf)
            afr[mf] = *(const long*)(ap + t * 2560 + mf * 128);
        #pragma unroll
        for (int nf = 0; nf < 8; ++nf) {
            long bfr = *(const long*)(brd + cur * BUFHALF + nf * 128);
            #pragma unroll
            for (int mf = 0; mf < 5; ++mf)
                acc[mf][nf] = __builtin_amdgcn_mfma_f32_16x16x32_fp8_fp8(afr[mf], bfr, acc[mf][nf], 0, 0, 0);
        }
    }

    // ---- fused log_softmax epilogue ----
    // C frag (mf,nf): row = mf*16 + g*4 + j, col = wave*128 + nf*16 + ln
    float bv[8];
    #pragma unroll
    for (int nf = 0; nf < 8; ++nf) bv[nf] = bfc[wave * 128 + nf * 16 + ln];
    #pragma unroll
    for (int mf = 0; mf < 5; ++mf)
        #pragma unroll
        for (int nf = 0; nf < 8; ++nf)
            #pragma unroll
            for (int j = 0; j < 4; ++j)
                acc[mf][nf][j] = acc[mf][nf][j] * WINV + bv[nf];

    float rmx[5][4];
    #pragma unroll
    for (int mf = 0; mf < 5; ++mf)
        #pragma unroll
        for (int j = 0; j < 4; ++j) {
            float mx = -3.0e38f;
            #pragma unroll
            for (int nf = 0; nf < 8; ++nf) mx = fmaxf(mx, acc[mf][nf][j]);
            #pragma unroll
            for (int s = 1; s < 16; s <<= 1) mx = fmaxf(mx, __shfl_xor(mx, s));
            rmx[mf][j] = mx;
        }
    if (ln == 0) {
        #pragma unroll
        for (int mf = 0; mf < 5; ++mf)
            #pragma unroll
            for (int j = 0; j < 4; ++j)
                red[wave][mf * 16 + g * 4 + j] = rmx[mf][j];
    }
    __syncthreads();
    #pragma unroll
    for (int mf = 0; mf < 5; ++mf)
        #pragma unroll
        for (int j = 0; j < 4; ++j) {
            const int r = mf * 16 + g * 4 + j;
            float mx = red[0][r];
            #pragma unroll
            for (int w = 1; w < 8; ++w) mx = fmaxf(mx, red[w][r]);
            rmx[mf][j] = mx;
        }
    __syncthreads();   // red reused for sums

    float rsm[5][4];
    #pragma unroll
    for (int mf = 0; mf < 5; ++mf)
        #pragma unroll
        for (int j = 0; j < 4; ++j) {
            float s = 0.f;
            #pragma unroll
            for (int nf = 0; nf < 8; ++nf) s += __expf(acc[mf][nf][j] - rmx[mf][j]);
            #pragma unroll
            for (int t2 = 1; t2 < 16; t2 <<= 1) s += __shfl_xor(s, t2);
            rsm[mf][j] = s;
        }
    if (ln == 0) {
        #pragma unroll
        for (int mf = 0; mf < 5; ++mf)
            #pragma unroll
            for (int j = 0; j < 4; ++j)
                red[wave][mf * 16 + g * 4 + j] = rsm[mf][j];
    }
    __syncthreads();
    #pragma unroll
    for (int mf = 0; mf < 5; ++mf)
        #pragma unroll
        for (int j = 0; j < 4; ++j) {
            const int r = mf * 16 + g * 4 + j;
            float s = 0.f;
            #pragma unroll
            for (int w = 0; w < 8; ++w) s += red[w][r];
            const float lse = rmx[mf][j] + __logf(s);
            float* op = out + (size_t)(m0 + r) * VV + wave * 128 + ln;
            #pragma unroll
            for (int nf = 0; nf < 8; ++nf)
                __builtin_nontemporal_store(acc[mf][nf][j] - lse, op + nf * 16);
        }
}

extern "C" void kernel_launch(void* const* d_in, const int* in_sizes, int n_in,
                              void* d_out, int out_size, void* d_ws, size_t ws_size,
                              hipStream_t stream) {
    const float* enc   = (const float*)d_in[0];
    const float* dec   = (const float*)d_in[1];
    const float* W_enc = (const float*)d_in[2];
    const float* b_enc = (const float*)d_in[3];
    const float* W_dec = (const float*)d_in[4];
    const float* b_dec = (const float*)d_in[5];
    const float* W_fc  = (const float*)d_in[6];
    const float* b_fc  = (const float*)d_in[7];
    float* out = (float*)d_out;

    float* encp = (float*)d_ws;                               // 1600*1024 f32, granule-major
    float* decp = encp + (size_t)BB * TT * DJ;                //  400*1024 f32, granule-major
    unsigned char* wfc8 = (unsigned char*)(decp + (size_t)BB * UU * DJ);  // 1 MB fp8, granule-major
    // total ws: 9.2 MB (same footprint as passing rounds)

    k_prep<<<dim3(189, 4), 256, 0, stream>>>(enc, dec, W_enc, b_enc, W_dec, b_dec, W_fc,
                                             encp, decp, wfc8);
    k_joint<<<M_TOTAL / MB, 512, 0, stream>>>(encp, decp, wfc8, b_fc, out);
}

// Round 16
// 324.363 us; speedup vs baseline: 1.7549x; 1.0465x over previous
//
#include <hip/hip_runtime.h>
#include <hip/hip_bf16.h>
#include <hip/hip_fp8.h>

#define TT 200
#define UU 50
#define BB 8
#define DJ 1024   // D_JOINT
#define DE 512    // D_ENC / D_DEC
#define VV 1024
#define M_TOTAL (BB*TT*UU)   // 80000
#define MB 80                // M rows per block
#define NITER 32             // K / 32
#define WINV (1.0f/32.0f)    // undo W_fc fp8 pre-scale

typedef float f32x4 __attribute__((ext_vector_type(4)));

__device__ __forceinline__ float fast_tanh(float x) {
    float e = __expf(2.f * x);
    return 1.f - 2.f / (e + 1.f);
}

__device__ __forceinline__ unsigned char f2fp8(float x) {
    return __hip_fp8_e4m3(x).__x;   // OCP e4m3, satfinite
}

__device__ __forceinline__ unsigned long long tanh_pack_fp8(float4 e0, float4 e1, float4 d0, float4 d1) {
    unsigned long long r;
    r  = (unsigned long long)f2fp8(fast_tanh(e0.x + d0.x));
    r |= (unsigned long long)f2fp8(fast_tanh(e0.y + d0.y)) << 8;
    r |= (unsigned long long)f2fp8(fast_tanh(e0.z + d0.z)) << 16;
    r |= (unsigned long long)f2fp8(fast_tanh(e0.w + d0.w)) << 24;
    r |= (unsigned long long)f2fp8(fast_tanh(e1.x + d1.x)) << 32;
    r |= (unsigned long long)f2fp8(fast_tanh(e1.y + d1.y)) << 40;
    r |= (unsigned long long)f2fp8(fast_tanh(e1.z + d1.z)) << 48;
    r |= (unsigned long long)f2fp8(fast_tanh(e1.w + d1.w)) << 56;
    return r;
}

// ---------- kernel 1: W_fc fp32 [n][k] -> fp8 e4m3 (x32) granule-major [gk][n] ----------
__global__ void k_wfct(const float* __restrict__ w, unsigned char* __restrict__ o) {
    const int G = blockIdx.x * 256 + threadIdx.x;   // 131072 granules
    const int gk = G >> 10, n = G & 1023;
    const float* src = w + (size_t)n * DJ + gk * 8;
    float4 a = *(const float4*)(src);
    float4 b = *(const float4*)(src + 4);
    unsigned long long r;
    r  = (unsigned long long)f2fp8(a.x * 32.f);
    r |= (unsigned long long)f2fp8(a.y * 32.f) << 8;
    r |= (unsigned long long)f2fp8(a.z * 32.f) << 16;
    r |= (unsigned long long)f2fp8(a.w * 32.f) << 24;
    r |= (unsigned long long)f2fp8(b.x * 32.f) << 32;
    r |= (unsigned long long)f2fp8(b.y * 32.f) << 40;
    r |= (unsigned long long)f2fp8(b.z * 32.f) << 48;
    r |= (unsigned long long)f2fp8(b.w * 32.f) << 56;
    *(unsigned long long*)(o + (size_t)G * 8) = r;
}

// ---------- kernel 2: projections -> GRANULE-MAJOR f32 [gk][rows][8] ----------
__global__ __launch_bounds__(256) void k_proj2(const float* __restrict__ enc,
                                               const float* __restrict__ dec,
                                               const float* __restrict__ W_enc,
                                               const float* __restrict__ b_enc,
                                               const float* __restrict__ W_dec,
                                               const float* __restrict__ b_dec,
                                               float* __restrict__ encp,
                                               float* __restrict__ decp) {
    __shared__ float in_s[16][DE];
    const bool isDec = blockIdx.x >= 100;
    const float* in  = isDec ? dec   : enc;
    const float* W   = isDec ? W_dec : W_enc;
    const float* bia = isDec ? b_dec : b_enc;
    float* out       = isDec ? decp  : encp;
    const int NR     = isDec ? (BB*UU) : (BB*TT);
    const int m0 = (isDec ? (blockIdx.x - 100) : blockIdx.x) * 16;
    const int tid = threadIdx.x;
    #pragma unroll
    for (int it = 0; it < 8; ++it) {
        int idx = tid + it * 256;
        int r = idx >> 7, c = (idx & 127) << 2;
        *(float4*)&in_s[r][c] = *(const float4*)(in + (size_t)(m0 + r) * DE + c);
    }
    __syncthreads();
    const int j = blockIdx.y * 256 + tid;
    const float4* wr = (const float4*)(W + (size_t)j * DE);
    float acc[16];
    #pragma unroll
    for (int r = 0; r < 16; ++r) acc[r] = 0.f;
    for (int d4 = 0; d4 < DE / 4; ++d4) {
        float4 w = wr[d4];
        #pragma unroll
        for (int r = 0; r < 16; ++r) {
            float4 x = *(const float4*)&in_s[r][d4 << 2];
            acc[r] += x.x * w.x + x.y * w.y + x.z * w.z + x.w * w.w;
        }
    }
    float bv = bia[j];
    const int gk = j >> 3, kl = j & 7;
    #pragma unroll
    for (int r = 0; r < 16; ++r)
        out[((size_t)gk * NR + (m0 + r)) * 8 + kl] = acc[r] + bv;
}

// ---------- kernel 3: fused tanh(enc+dec) @ W_fc^T + b_fc -> log_softmax ----------
// 512 threads (8 waves), 80 M x 1024 N, fp8 GEMM, barrier-free main loop.
// Register double-buffer of A/B fragments (8B longs); waves free-run at different
// phases -> s_setprio(1) around the MFMA cluster (T5, pays on free-running waves).
__global__ __launch_bounds__(512, 2) void k_joint(const float* __restrict__ encp,
                                                  const float* __restrict__ decp,
                                                  const unsigned char* __restrict__ wfc8,
                                                  const float* __restrict__ bfc,
                                                  float* __restrict__ out) {
    __shared__ unsigned char As[81920];      // 80 KB: granule (gkf 0..127, m 0..79)
    __shared__ float red[8][MB];             // 2.5 KB

    const int tid = threadIdx.x;
    const int wave = tid >> 6, lane = tid & 63;
    const int g = lane >> 4, ln = lane & 15;
    const int bid = blockIdx.x;
    const int m0 = bid * MB;

    // ---- prologue: compute A-stripe into LDS ----
    for (int r = 0; r < 20; ++r) {
        const int gidx = r * 512 + tid;          // 10240 granules: gkf*80 + m
        const int gkf = gidx / MB;
        const int m = gidx - gkf * MB;
        const int mrow = m0 + m;
        const int b = mrow / (TT * UU);
        const int rem = mrow - b * (TT * UU);
        const int t = rem / UU;
        const int u = rem - t * UU;
        const float* ep = encp + ((size_t)gkf * (BB * TT) + b * TT + t) * 8;
        const float* dp = decp + ((size_t)gkf * (BB * UU) + b * UU + u) * 8;
        float4 e0 = *(const float4*)(ep);
        float4 e1 = *(const float4*)(ep + 4);
        float4 d0 = *(const float4*)(dp);
        float4 d1 = *(const float4*)(dp + 4);
        *(unsigned long long*)&As[(size_t)gidx * 8] = tanh_pack_fp8(e0, e1, d0, d1);
    }

    f32x4 acc[5][8];
    #pragma unroll
    for (int mf = 0; mf < 5; ++mf)
        #pragma unroll
        for (int nf = 0; nf < 8; ++nf)
            acc[mf][nf] = (f32x4){0.f, 0.f, 0.f, 0.f};

    __syncthreads();   // As ready; the ONLY main-path barrier

    // per-wave B base: granule (gk, n) at wfc8 + (gk*1024 + n)*8
    const unsigned char* bbase = wfc8 + (size_t)(wave * 128 + ln) * 8;

    long bcur[8], bnxt[8], acur[5], anxt[5];
    {
        const int k0 = bid & 31;
        #pragma unroll
        for (int nf = 0; nf < 8; ++nf)
            bcur[nf] = *(const long*)(bbase + ((size_t)(k0 * 4 + g) * 1024 + nf * 16) * 8);
        #pragma unroll
        for (int mf = 0; mf < 5; ++mf)
            acur[mf] = *(const long*)&As[(size_t)((k0 * 4 + g) * MB + mf * 16 + ln) * 8];
    }

#define STEP(CA, CB, NA, NB, T)                                                           \
    do {                                                                                  \
        if ((T) < NITER - 1) {                                                            \
            const int kn = ((T) + 1 + bid) & 31;                                          \
            _Pragma("unroll")                                                             \
            for (int nf = 0; nf < 8; ++nf)                                                \
                NB[nf] = *(const long*)(bbase + ((size_t)(kn * 4 + g) * 1024 + nf * 16) * 8); \
            _Pragma("unroll")                                                             \
            for (int mf = 0; mf < 5; ++mf)                                                \
                NA[mf] = *(const long*)&As[(size_t)((kn * 4 + g) * MB + mf * 16 + ln) * 8];   \
        }                                                                                 \
        __builtin_amdgcn_s_setprio(1);                                                    \
        _Pragma("unroll")                                                                 \
        for (int nf = 0; nf < 8; ++nf)                                                    \
            _Pragma("unroll")                                                             \
            for (int mf = 0; mf < 5; ++mf)                                                \
                acc[mf][nf] = __builtin_amdgcn_mfma_f32_16x16x32_fp8_fp8(                 \
                    CA[mf], CB[nf], acc[mf][nf], 0, 0, 0);                                \
        __builtin_amdgcn_s_setprio(0);                                                    \
    } while (0)

    for (int t = 0; t < NITER; t += 2) {
        STEP(acur, bcur, anxt, bnxt, t);
        STEP(anxt, bnxt, acur, bcur, t + 1);
    }
#undef STEP

    // ---- fused log_softmax epilogue ----
    // C frag (mf,nf): row = mf*16 + g*4 + j, col = wave*128 + nf*16 + ln
    float bv[8];
    #pragma unroll
    for (int nf = 0; nf < 8; ++nf) bv[nf] = bfc[wave * 128 + nf * 16 + ln];
    #pragma unroll
    for (int mf = 0; mf < 5; ++mf)
        #pragma unroll
        for (int nf = 0; nf < 8; ++nf)
            #pragma unroll
            for (int j = 0; j < 4; ++j)
                acc[mf][nf][j] = acc[mf][nf][j] * WINV + bv[nf];

    float rmx[5][4];
    #pragma unroll
    for (int mf = 0; mf < 5; ++mf)
        #pragma unroll
        for (int j = 0; j < 4; ++j) {
            float mx = -3.0e38f;
            #pragma unroll
            for (int nf = 0; nf < 8; ++nf) mx = fmaxf(mx, acc[mf][nf][j]);
            #pragma unroll
            for (int s = 1; s < 16; s <<= 1) mx = fmaxf(mx, __shfl_xor(mx, s));
            rmx[mf][j] = mx;
        }
    if (ln == 0) {
        #pragma unroll
        for (int mf = 0; mf < 5; ++mf)
            #pragma unroll
            for (int j = 0; j < 4; ++j)
                red[wave][mf * 16 + g * 4 + j] = rmx[mf][j];
    }
    __syncthreads();
    #pragma unroll
    for (int mf = 0; mf < 5; ++mf)
        #pragma unroll
        for (int j = 0; j < 4; ++j) {
            const int r = mf * 16 + g * 4 + j;
            float mx = red[0][r];
            #pragma unroll
            for (int w = 1; w < 8; ++w) mx = fmaxf(mx, red[w][r]);
            rmx[mf][j] = mx;
        }
    __syncthreads();   // red reused for sums

    float rsm[5][4];
    #pragma unroll
    for (int mf = 0; mf < 5; ++mf)
        #pragma unroll
        for (int j = 0; j < 4; ++j) {
            float s = 0.f;
            #pragma unroll
            for (int nf = 0; nf < 8; ++nf) s += __expf(acc[mf][nf][j] - rmx[mf][j]);
            #pragma unroll
            for (int t2 = 1; t2 < 16; t2 <<= 1) s += __shfl_xor(s, t2);
            rsm[mf][j] = s;
        }
    if (ln == 0) {
        #pragma unroll
        for (int mf = 0; mf < 5; ++mf)
            #pragma unroll
            for (int j = 0; j < 4; ++j)
                red[wave][mf * 16 + g * 4 + j] = rsm[mf][j];
    }
    __syncthreads();
    #pragma unroll
    for (int mf = 0; mf < 5; ++mf)
        #pragma unroll
        for (int j = 0; j < 4; ++j) {
            const int r = mf * 16 + g * 4 + j;
            float s = 0.f;
            #pragma unroll
            for (int w = 0; w < 8; ++w) s += red[w][r];
            const float lse = rmx[mf][j] + __logf(s);
            float* op = out + (size_t)(m0 + r) * VV + wave * 128 + ln;
            #pragma unroll
            for (int nf = 0; nf < 8; ++nf)
                __builtin_nontemporal_store(acc[mf][nf][j] - lse, op + nf * 16);
        }
}

extern "C" void kernel_launch(void* const* d_in, const int* in_sizes, int n_in,
                              void* d_out, int out_size, void* d_ws, size_t ws_size,
                              hipStream_t stream) {
    const float* enc   = (const float*)d_in[0];
    const float* dec   = (const float*)d_in[1];
    const float* W_enc = (const float*)d_in[2];
    const float* b_enc = (const float*)d_in[3];
    const float* W_dec = (const float*)d_in[4];
    const float* b_dec = (const float*)d_in[5];
    const float* W_fc  = (const float*)d_in[6];
    const float* b_fc  = (const float*)d_in[7];
    float* out = (float*)d_out;

    float* encp = (float*)d_ws;                               // 1600*1024 f32, granule-major
    float* decp = encp + (size_t)BB * TT * DJ;                //  400*1024 f32, granule-major
    unsigned char* wfc8 = (unsigned char*)(decp + (size_t)BB * UU * DJ);  // 1 MB fp8, granule-major
    // total ws: 9.2 MB (same footprint as passing rounds)

    k_wfct<<<(VV * DJ) / (256 * 8), 256, 0, stream>>>(W_fc, wfc8);
    k_proj2<<<dim3(125, DJ / 256), 256, 0, stream>>>(enc, dec, W_enc, b_enc, W_dec, b_dec, encp, decp);
    k_joint<<<M_TOTAL / MB, 512, 0, stream>>>(encp, decp, wfc8, b_fc, out);
}